// Round 2
// baseline (84.812 us; speedup 1.0000x reference)
//
#include <hip/hip_runtime.h>
#include <math.h>

#define NQ 10
#define NLAYERS 4
#define NGATES (NLAYERS * NQ)

typedef float v2f __attribute__((ext_vector_type(2)));
typedef float v4f __attribute__((ext_vector_type(4)));

__device__ __forceinline__ v2f mk2(float a, float b) { v2f r; r.x = a; r.y = b; return r; }

// ---- scalar complex helpers (explicit fmaf -> full-rate v_fma_f32 pipe) ----
__device__ __forceinline__ v2f cmulS(v2f a, v2f b) {
    return mk2(fmaf(a.x, b.x, -(a.y * b.y)), fmaf(a.x, b.y, a.y * b.x));
}
// SU(2) gate m = {a,b,c,d} = {re00,im00,re01,im01}; u10=-conj(u01), u11=conj(u00)
__device__ __forceinline__ v2f grow0(v4f m, v2f s0, v2f s1) {   // u00*s0 + u01*s1
    float re = fmaf(m.x, s0.x, fmaf(-m.y, s0.y, fmaf(m.z, s1.x, -(m.w * s1.y))));
    float im = fmaf(m.x, s0.y, fmaf( m.y, s0.x, fmaf(m.z, s1.y,   m.w * s1.x)));
    return mk2(re, im);
}
__device__ __forceinline__ v2f grow1(v4f m, v2f s0, v2f s1) {   // -conj(u01)*s0 + conj(u00)*s1
    float re = fmaf(-m.z, s0.x, fmaf(-m.w, s0.y, fmaf(m.x, s1.x,   m.y * s1.y)));
    float im = fmaf( m.w, s0.x, fmaf(-m.z, s0.y, fmaf(m.x, s1.y, -(m.y * s1.x))));
    return mk2(re, im);
}

// CNOT-ring permutations (GF(2)-linear; closed forms verified previous session)
__host__ __device__ constexpr int pxor1(int v) {   // off = 1 (even layers)
    int y = v; y ^= y >> 1; y ^= y >> 2; y ^= y >> 4; y ^= y >> 8;
    return (y & 0x1FF) | (((y ^ (v >> 9)) & 1) << 9);
}
__host__ __device__ constexpr int pxor5(int v) {   // off = 5 (odd layers)
    int lo = v & 31, hi = (v >> 5) & 31;
    return (lo << 5) | (lo ^ hi);
}

// 1-qubit gate on register bit b (indices constant after unroll); one v4f mat
__device__ __forceinline__ void apply_gate(v2f* st, v4f m, int b) {
    #pragma unroll
    for (int g = 0; g < 16; ++g) {
        int r0 = ((g >> b) << (b + 1)) | (g & ((1 << b) - 1));
        int r1 = r0 | (1 << b);
        v2f s0 = st[r0], s1 = st[r1];
        st[r0] = grow0(m, s0, s1);
        st[r1] = grow1(m, s0, s1);
    }
}

// contiguous reload: lane L owns 32 consecutive v2f at element 34*L (16B-aligned)
__device__ __forceinline__ void load_contig(v2f* st, const v2f* scratch, int lane) {
    const v4f* rp = (const v4f*)(scratch + 34 * lane);
    #pragma unroll
    for (int k = 0; k < 16; ++k) { v4f t = rp[k]; st[2 * k] = t.xy; st[2 * k + 1] = t.zw; }
}

// Layouts (2 samples/wave; s = lane>>5, sl = lane&31; amp idx bits [9:0], qubit q = bit 9-q):
//  A2: reg r = idx[4:0] (qubits 5..9 on reg bits 4..0), lane = idx[9:5] (qubits 0..4 on lane bits 4..0)
//  B2: reg r = idx[9:5] (qubits 0..4), lane = idx[4:0] (qubits 5..9)
//  LDS slot: loc = 34*newlane + newreg (stride 34: bank-floor writes, 16B-aligned b128 reads)
// Layer 0's rotations are folded into the encoding factors; layer 0's CNOT perm (P0) is
// folded into the INIT evaluation (P0^-1 = adjacent-bit XOR); layer 3's perm into signs.
__global__ __launch_bounds__(64) void qsim_kernel(const float* __restrict__ x,
                                                  const float* __restrict__ w,
                                                  float* __restrict__ out)
{
    __shared__ __align__(16) v2f scratch[2176];
    __shared__ __align__(16) v4f matsL[NGATES];      // one v4f per gate
    __shared__ __align__(16) v2f encf[2][NQ][2];

    const int lane = threadIdx.x;
    const int s = lane >> 5, sl = lane & 31;
    const long sample = 2L * blockIdx.x + s;

    // ---- per-block setup: 40 variational gates, single v4f each ----
    if (lane < NGATES) {
        float w0 = w[lane * 3 + 0], w1 = w[lane * 3 + 1], w2 = w[lane * 3 + 2];
        float hs = 0.5f * (w0 + w2), hd = 0.5f * (w0 - w2), hy = 0.5f * w1;
        float cy, sy, cs, ss, cd, sd;
        sincosf(hy, &sy, &cy);
        sincosf(hs, &ss, &cs);
        sincosf(hd, &sd, &cd);
        v4f m; m.x = cy * cs; m.y = -cy * ss; m.z = -sy * cd; m.w = -sy * sd;
        matsL[lane] = m;   // {re00, im00, re01, im01} of RZ(w2)RY(w1)RZ(w0)
    }
    __syncthreads();

    // ---- encoding factors with layer-0 rotations folded: g_q = U_{0,q} * f_q ----
    if (sl < NQ) {
        const float* xs = x + sample * (2 * NQ);
        float th = 0.7853981633974483f * (xs[sl] + 1.0f);
        float ph = 0.7853981633974483f * (xs[NQ + sl] + 1.0f);
        float cy, sy, cp, sp;
        sincosf(th, &sy, &cy);
        sincosf(ph, &sp, &cp);
        const float inv = 0.7071067811865476f;
        float a = (cy - sy) * inv, b = (cy + sy) * inv;
        v2f f0 = mk2(cp * a, -sp * a);   // column 0 of RZ(phi) RY(theta) H
        v2f f1 = mk2(cp * b,  sp * b);
        v4f m = matsL[sl];               // own-lane RAW through LDS after barrier: safe
        encf[s][sl][0] = grow0(m, f0, f1);
        encf[s][sl][1] = grow1(m, f0, f1);
    }
    __syncthreads();

    // ---- product-state init DIRECTLY in layout A2 with P0 folded ----
    // P0^-1(j) bit for qubit q (arg of factor g_q), with j[4:0]=reg r, j[9:5]=lane sl:
    //  q0: L4^r0   q1: L3^L4^r0   q2: L2^L3   q3: L1^L2   q4: L0^L1
    //  q5: r4^L0   q6: r3^r4      q7: r2^r3   q8: r1^r2   q9: r0^r1
    v2f st[32];
    {
        v2f Lc = cmulS(encf[s][2][((sl >> 2) ^ (sl >> 3)) & 1],
                 cmulS(encf[s][3][((sl >> 1) ^ (sl >> 2)) & 1],
                       encf[s][4][(sl ^ (sl >> 1)) & 1]));
        // g5 keyed by t = r4, arg t ^ L0
        v2f g5s0 = encf[s][5][sl & 1];
        v2f g5s1 = encf[s][5][(sl & 1) ^ 1];
        // h[t] = g0[t ^ L4] * g1[t ^ L3 ^ L4]  (t = r0)
        const int l4 = (sl >> 4) & 1, l34 = ((sl >> 3) ^ (sl >> 4)) & 1;
        v2f h0 = cmulS(encf[s][0][l4],     encf[s][1][l34]);
        v2f h1 = cmulS(encf[s][0][l4 ^ 1], encf[s][1][l34 ^ 1]);
        // k4[(r1<<1)|r0] = g9[r1^r0] * h[r0]
        v2f k4[4];
        k4[0] = cmulS(encf[s][9][0], h0);
        k4[1] = cmulS(encf[s][9][1], h1);
        k4[2] = cmulS(encf[s][9][1], h0);
        k4[3] = cmulS(encf[s][9][0], h1);
        v2f Av[2], Bv[4], Cv[8], Dv[16];
        Av[0] = cmulS(Lc, g5s0); Av[1] = cmulS(Lc, g5s1);
        #pragma unroll
        for (int i = 0; i < 4; ++i)  Bv[i] = cmulS(Av[i >> 1], encf[s][6][((i >> 1) ^ i) & 1]);
        #pragma unroll
        for (int i = 0; i < 8; ++i)  Cv[i] = cmulS(Bv[i >> 1], encf[s][7][((i >> 1) ^ i) & 1]);
        #pragma unroll
        for (int i = 0; i < 16; ++i) Dv[i] = cmulS(Cv[i >> 1], encf[s][8][((i >> 1) ^ i) & 1]);
        #pragma unroll
        for (int r = 0; r < 32; ++r) st[r] = cmulS(Dv[r >> 1], k4[r & 3]);
    }

    const int jb1 = pxor1(sl), jb5 = pxor5(sl);   // P(idx) = P(r<<5) ^ P(sl)

    // ---- layers 1..3 (state starts in A2, post-P0) ----
    #pragma unroll
    for (int l = 1; l < NLAYERS; ++l) {
        const v4f* Ml = matsL + l * NQ;
        // gates on qubits 5..9 in A2 (reg bit 9-q)
        apply_gate(st, Ml[5], 4);
        apply_gate(st, Ml[6], 3);
        apply_gate(st, Ml[7], 2);
        apply_gate(st, Ml[8], 1);
        apply_gate(st, Ml[9], 0);

        // swap A2 -> B2
        __syncthreads();
        {
            v2f* wp = scratch + 1088 * s + sl;
            #pragma unroll
            for (int r = 0; r < 32; ++r) wp[34 * r] = st[r];
        }
        __syncthreads();
        load_contig(st, scratch, lane);

        // gates on qubits 0..4 in B2 (reg bit 4-q)
        apply_gate(st, Ml[0], 4);
        apply_gate(st, Ml[1], 3);
        apply_gate(st, Ml[2], 2);
        apply_gate(st, Ml[3], 1);
        apply_gate(st, Ml[4], 0);

        if (l < NLAYERS - 1) {
            // perm-swap B2 -> A2 with CNOT ring folded into scatter addresses
            __syncthreads();
            #pragma unroll
            for (int r = 0; r < 32; ++r) {
                const int jc = (l & 1) ? pxor5(r << 5) : pxor1(r << 5);  // compile-time
                const int j = jc ^ ((l & 1) ? jb5 : jb1);
                scratch[1088 * s + 34 * (j >> 5) + (j & 31)] = st[r];
            }
            __syncthreads();
            load_contig(st, scratch, lane);
        }
    }

    // ---- measurement in B2 with layer-3 perm (pxor5) folded into signs ----
    // true final index j: j[9:5] = sl, j[4:0] = sl ^ r
    {
        float p[32];
        #pragma unroll
        for (int r = 0; r < 32; ++r) {
            v2f a = st[r];
            p[r] = fmaf(a.x, a.x, a.y * a.y);
        }
        float t0 = 0.f, t1 = 0.f, t2 = 0.f, t3 = 0.f, t4 = 0.f;
        float s0a[16], s1a[8], s2a[4], s3a[2];
        #pragma unroll
        for (int k = 0; k < 16; ++k) { s0a[k] = p[2*k] + p[2*k+1]; t0 += p[2*k] - p[2*k+1]; }
        #pragma unroll
        for (int k = 0; k < 8; ++k)  { s1a[k] = s0a[2*k] + s0a[2*k+1]; t1 += s0a[2*k] - s0a[2*k+1]; }
        #pragma unroll
        for (int k = 0; k < 4; ++k)  { s2a[k] = s1a[2*k] + s1a[2*k+1]; t2 += s1a[2*k] - s1a[2*k+1]; }
        #pragma unroll
        for (int k = 0; k < 2; ++k)  { s3a[k] = s2a[2*k] + s2a[2*k+1]; t3 += s2a[2*k] - s2a[2*k+1]; }
        float S = s3a[0] + s3a[1];   t4 = s3a[0] - s3a[1];

        float acc[NQ];
        // q=0..4: j bit (9-q) = sl bit (4-q)
        #pragma unroll
        for (int q = 0; q < 5; ++q)
            acc[q] = ((sl >> (4 - q)) & 1) ? -S : S;
        // q=5..9: j bit k=9-q = sl_k ^ r_k  ->  lane-sign * reg-tree t_k
        acc[5] = ((sl >> 4) & 1) ? -t4 : t4;
        acc[6] = ((sl >> 3) & 1) ? -t3 : t3;
        acc[7] = ((sl >> 2) & 1) ? -t2 : t2;
        acc[8] = ((sl >> 1) & 1) ? -t1 : t1;
        acc[9] = (sl & 1)        ? -t0 : t0;

        // butterfly over the 5 lane bits (stays within each 32-lane half)
        #pragma unroll
        for (int q = 0; q < NQ; ++q) {
            #pragma unroll
            for (int o = 16; o >= 1; o >>= 1)
                acc[q] += __shfl_xor(acc[q], o);
        }
        float v = acc[0];
        #pragma unroll
        for (int q = 1; q < NQ; ++q) v = (sl == q) ? acc[q] : v;
        if (sl < NQ)
            out[sample * NQ + sl] = v;
    }
}

extern "C" void kernel_launch(void* const* d_in, const int* in_sizes, int n_in,
                              void* d_out, int out_size, void* d_ws, size_t ws_size,
                              hipStream_t stream) {
    const float* x = (const float*)d_in[0];   // (16,256,20) fp32
    const float* w = (const float*)d_in[1];   // (4,10,3)   fp32
    float* out = (float*)d_out;               // (16,256,10) fp32
    const int n_samples = in_sizes[0] / (2 * NQ);  // 4096
    qsim_kernel<<<n_samples / 2, 64, 0, stream>>>(x, w, out);
}

// Round 3
// 77.258 us; speedup vs baseline: 1.0978x; 1.0978x over previous
//
#include <hip/hip_runtime.h>
#include <math.h>

#define NQ 10
#define NLAYERS 4
#define NGATES (NLAYERS * NQ)

typedef float v2f __attribute__((ext_vector_type(2)));
typedef float v4f __attribute__((ext_vector_type(4)));

__device__ __forceinline__ v2f mk2(float a, float b) { v2f r; r.x = a; r.y = b; return r; }

// Packed gate entry m = {re, re, -im, im}; all complex math as v_pk_fma_f32.
__device__ __forceinline__ v2f cmul(v2f a, v2f b) {              // generic {re,im} mul
    v2f r = a.xx * b;
    return __builtin_elementwise_fma(mk2(-a.y, a.y), b.yx, r);
}
__device__ __forceinline__ v4f pack_u(float re, float im) {
    v4f m; m.x = re; m.y = re; m.z = -im; m.w = im; return m;
}
// SU(2) row0: u00*s0 + u01*s1   (m0 = packed u00, m1 = packed u01)
__device__ __forceinline__ v2f g0pk(v4f m0, v4f m1, v2f s0, v2f s1) {
    v2f r = m0.xy * s0;
    r = __builtin_elementwise_fma(m0.zw, s0.yx, r);
    r = __builtin_elementwise_fma(m1.xy, s1, r);
    r = __builtin_elementwise_fma(m1.zw, s1.yx, r);
    return r;
}
// SU(2) row1: -conj(u01)*s0 + conj(u00)*s1  (negs fold into VOP3P neg modifiers)
__device__ __forceinline__ v2f g1pk(v4f m0, v4f m1, v2f s0, v2f s1) {
    v2f r = m1.zw * s0.yx;
    r = __builtin_elementwise_fma(-m1.xy, s0, r);
    r = __builtin_elementwise_fma(m0.xy, s1, r);
    r = __builtin_elementwise_fma(-m0.zw, s1.yx, r);
    return r;
}

// CNOT-ring permutations (GF(2)-linear; closed forms verified earlier sessions)
__host__ __device__ constexpr int pxor1(int v) {   // off = 1 (even layers)
    int y = v; y ^= y >> 1; y ^= y >> 2; y ^= y >> 4; y ^= y >> 8;
    return (y & 0x1FF) | (((y ^ (v >> 9)) & 1) << 9);
}
__host__ __device__ constexpr int pxor5(int v) {   // off = 5 (odd layers)
    int lo = v & 31, hi = (v >> 5) & 31;
    return (lo << 5) | (lo ^ hi);
}

// 1-qubit gate on register bit b (b compile-time; indices constant after unroll)
__device__ __forceinline__ void apply_gate(v2f* st, v4f m0, v4f m1, int b) {
    #pragma unroll
    for (int g = 0; g < 16; ++g) {
        int r0 = ((g >> b) << (b + 1)) | (g & ((1 << b) - 1));
        int r1 = r0 | (1 << b);
        v2f s0 = st[r0], s1 = st[r1];
        st[r0] = g0pk(m0, m1, s0, s1);
        st[r1] = g1pk(m0, m1, s0, s1);
    }
}

// contiguous reload: lane L owns 32 consecutive v2f at element 34*L (16B-aligned)
__device__ __forceinline__ void load_contig(v2f* st, const v2f* scratch, int lane) {
    const v4f* rp = (const v4f*)(scratch + 34 * lane);
    #pragma unroll
    for (int k = 0; k < 16; ++k) { v4f t = rp[k]; st[2 * k] = t.xy; st[2 * k + 1] = t.zw; }
}

// Layouts (2 samples/wave; s = lane>>5, sl = lane&31; amp idx bits [9:0], qubit q = bit 9-q):
//  A2: reg r = idx[4:0] (qubits 5..9 on reg bits 4..0), lane = idx[9:5] (qubits 0..4)
//  B2: reg r = idx[9:5] (qubits 0..4), lane = idx[4:0] (qubits 5..9)
//  LDS slot: loc = 34*newlane + newreg (stride 34: bank-floor writes, 16B-aligned b128 reads)
// Layer 0's rotations folded into encoding factors; layer 0's CNOT perm (P0) folded into
// the init evaluation (P0^-1 = adjacent-bit XOR); layer 3's perm folded into measurement
// signs. The 3 variational layers run in a REAL loop (code-size / L1I reuse).
__global__ __launch_bounds__(64) void qsim_kernel(const float* __restrict__ x,
                                                  const float* __restrict__ w,
                                                  float* __restrict__ out)
{
    __shared__ __align__(16) v2f scratch[2176];
    __shared__ __align__(16) v4f matsL[NGATES * 2];   // packed u00,u01 per gate
    __shared__ __align__(16) v2f encf[2][NQ][2];

    const int lane = threadIdx.x;
    const int s = lane >> 5, sl = lane & 31;
    const long sample = 2L * blockIdx.x + s;

    // ---- per-block setup: 40 variational gates (u00,u01 packed) ----
    if (lane < NGATES) {
        float w0 = w[lane * 3 + 0], w1 = w[lane * 3 + 1], w2 = w[lane * 3 + 2];
        float hs = 0.5f * (w0 + w2), hd = 0.5f * (w0 - w2), hy = 0.5f * w1;
        float cy, sy, cs, ss, cd, sd;
        sincosf(hy, &sy, &cy);
        sincosf(hs, &ss, &cs);
        sincosf(hd, &sd, &cd);
        matsL[lane * 2 + 0] = pack_u( cy * cs, -cy * ss);   // u00 of RZ(w2)RY(w1)RZ(w0)
        matsL[lane * 2 + 1] = pack_u(-sy * cd, -sy * sd);   // u01
    }
    __syncthreads();

    // ---- encoding factors with layer-0 rotations folded: g_q = U_{0,q} * f_q ----
    if (sl < NQ) {
        const float* xs = x + sample * (2 * NQ);
        float th = 0.7853981633974483f * (xs[sl] + 1.0f);
        float ph = 0.7853981633974483f * (xs[NQ + sl] + 1.0f);
        float cy, sy, cp, sp;
        sincosf(th, &sy, &cy);
        sincosf(ph, &sp, &cp);
        const float inv = 0.7071067811865476f;
        float a = (cy - sy) * inv, b = (cy + sy) * inv;
        v2f f0 = mk2(cp * a, -sp * a);   // column 0 of RZ(phi) RY(theta) H
        v2f f1 = mk2(cp * b,  sp * b);
        v4f M0 = matsL[sl * 2 + 0], M1 = matsL[sl * 2 + 1];  // own-lane RAW: safe
        encf[s][sl][0] = g0pk(M0, M1, f0, f1);
        encf[s][sl][1] = g1pk(M0, M1, f0, f1);
    }
    __syncthreads();

    // ---- product-state init DIRECTLY in layout A2 with P0 folded ----
    // P0^-1(j) bit for factor g_q, with j[4:0]=reg r, j[9:5]=lane sl:
    //  q0: L4^r0   q1: L3^L4^r0   q2: L2^L3   q3: L1^L2   q4: L0^L1
    //  q5: r4^L0   q6: r3^r4      q7: r2^r3   q8: r1^r2   q9: r0^r1
    v2f st[32];
    {
        v2f Lc = cmul(encf[s][2][((sl >> 2) ^ (sl >> 3)) & 1],
                 cmul(encf[s][3][((sl >> 1) ^ (sl >> 2)) & 1],
                      encf[s][4][(sl ^ (sl >> 1)) & 1]));
        v2f g5s0 = encf[s][5][sl & 1];          // g5 keyed by t = r4, arg t ^ L0
        v2f g5s1 = encf[s][5][(sl & 1) ^ 1];
        const int l4 = (sl >> 4) & 1, l34 = ((sl >> 3) ^ (sl >> 4)) & 1;
        v2f h0 = cmul(encf[s][0][l4],     encf[s][1][l34]);   // h[t=r0]
        v2f h1 = cmul(encf[s][0][l4 ^ 1], encf[s][1][l34 ^ 1]);
        v2f k4[4];                               // k4[(r1<<1)|r0] = g9[r1^r0] * h[r0]
        k4[0] = cmul(encf[s][9][0], h0);
        k4[1] = cmul(encf[s][9][1], h1);
        k4[2] = cmul(encf[s][9][1], h0);
        k4[3] = cmul(encf[s][9][0], h1);
        v2f Av[2], Bv[4], Cv[8], Dv[16];
        Av[0] = cmul(Lc, g5s0); Av[1] = cmul(Lc, g5s1);
        #pragma unroll
        for (int i = 0; i < 4; ++i)  Bv[i] = cmul(Av[i >> 1], encf[s][6][((i >> 1) ^ i) & 1]);
        #pragma unroll
        for (int i = 0; i < 8; ++i)  Cv[i] = cmul(Bv[i >> 1], encf[s][7][((i >> 1) ^ i) & 1]);
        #pragma unroll
        for (int i = 0; i < 16; ++i) Dv[i] = cmul(Cv[i >> 1], encf[s][8][((i >> 1) ^ i) & 1]);
        #pragma unroll
        for (int r = 0; r < 32; ++r) st[r] = cmul(Dv[r >> 1], k4[r & 3]);
    }

    const int jb1 = pxor1(sl), jb5 = pxor5(sl);   // P(idx) = P(r<<5) ^ P(sl)

    // ---- layers 1..3: REAL loop (l runtime -> ~1/3 the code, L1I-resident) ----
    #pragma unroll 1
    for (int l = 1; l < NLAYERS; ++l) {
        const v4f* Ml = matsL + l * NQ * 2;
        // gates on qubits 5..9 in A2 (reg bit 9-q)
        apply_gate(st, Ml[5*2], Ml[5*2+1], 4);
        apply_gate(st, Ml[6*2], Ml[6*2+1], 3);
        apply_gate(st, Ml[7*2], Ml[7*2+1], 2);
        apply_gate(st, Ml[8*2], Ml[8*2+1], 1);
        apply_gate(st, Ml[9*2], Ml[9*2+1], 0);

        // swap A2 -> B2
        __syncthreads();
        {
            v2f* wp = scratch + 1088 * s + sl;
            #pragma unroll
            for (int r = 0; r < 32; ++r) wp[34 * r] = st[r];
        }
        __syncthreads();
        load_contig(st, scratch, lane);

        // gates on qubits 0..4 in B2 (reg bit 4-q)
        apply_gate(st, Ml[0*2], Ml[0*2+1], 4);
        apply_gate(st, Ml[1*2], Ml[1*2+1], 3);
        apply_gate(st, Ml[2*2], Ml[2*2+1], 2);
        apply_gate(st, Ml[3*2], Ml[3*2+1], 1);
        apply_gate(st, Ml[4*2], Ml[4*2+1], 0);

        if (l < NLAYERS - 1) {
            // perm-swap B2 -> A2, CNOT ring folded into scatter addresses;
            // layer parity selects the (compile-time) per-r constants via SALU cselect.
            __syncthreads();
            const bool odd = (l & 1);
            const int jb = odd ? jb5 : jb1;
            #pragma unroll
            for (int r = 0; r < 32; ++r) {
                const int jc = odd ? pxor5(r << 5) : pxor1(r << 5);  // 2 consts, cselect
                const int j = jc ^ jb;
                scratch[1088 * s + 34 * (j >> 5) + (j & 31)] = st[r];
            }
            __syncthreads();
            load_contig(st, scratch, lane);
        }
    }

    // ---- measurement in B2 with layer-3 perm (pxor5) folded into signs ----
    // true final index j: j[9:5] = sl, j[4:0] = sl ^ r
    {
        float p[32];
        #pragma unroll
        for (int r = 0; r < 32; ++r) {
            v2f a = st[r];
            v2f sq = a * a;
            p[r] = sq.x + sq.y;
        }
        float t0 = 0.f, t1 = 0.f, t2 = 0.f, t3 = 0.f, t4 = 0.f;
        float s0a[16], s1a[8], s2a[4], s3a[2];
        #pragma unroll
        for (int k = 0; k < 16; ++k) { s0a[k] = p[2*k] + p[2*k+1]; t0 += p[2*k] - p[2*k+1]; }
        #pragma unroll
        for (int k = 0; k < 8; ++k)  { s1a[k] = s0a[2*k] + s0a[2*k+1]; t1 += s0a[2*k] - s0a[2*k+1]; }
        #pragma unroll
        for (int k = 0; k < 4; ++k)  { s2a[k] = s1a[2*k] + s1a[2*k+1]; t2 += s1a[2*k] - s1a[2*k+1]; }
        #pragma unroll
        for (int k = 0; k < 2; ++k)  { s3a[k] = s2a[2*k] + s2a[2*k+1]; t3 += s2a[2*k] - s2a[2*k+1]; }
        float S = s3a[0] + s3a[1];   t4 = s3a[0] - s3a[1];

        float acc[NQ];
        // q=0..4: j bit (9-q) = sl bit (4-q)
        #pragma unroll
        for (int q = 0; q < 5; ++q)
            acc[q] = ((sl >> (4 - q)) & 1) ? -S : S;
        // q=5..9: j bit k=9-q = sl_k ^ r_k  ->  lane-sign * reg-tree t_k
        acc[5] = ((sl >> 4) & 1) ? -t4 : t4;
        acc[6] = ((sl >> 3) & 1) ? -t3 : t3;
        acc[7] = ((sl >> 2) & 1) ? -t2 : t2;
        acc[8] = ((sl >> 1) & 1) ? -t1 : t1;
        acc[9] = (sl & 1)        ? -t0 : t0;

        // butterfly over the 5 lane bits (stays within each 32-lane half)
        #pragma unroll
        for (int q = 0; q < NQ; ++q) {
            #pragma unroll
            for (int o = 16; o >= 1; o >>= 1)
                acc[q] += __shfl_xor(acc[q], o);
        }
        float v = acc[0];
        #pragma unroll
        for (int q = 1; q < NQ; ++q) v = (sl == q) ? acc[q] : v;
        if (sl < NQ)
            out[sample * NQ + sl] = v;
    }
}

extern "C" void kernel_launch(void* const* d_in, const int* in_sizes, int n_in,
                              void* d_out, int out_size, void* d_ws, size_t ws_size,
                              hipStream_t stream) {
    const float* x = (const float*)d_in[0];   // (16,256,20) fp32
    const float* w = (const float*)d_in[1];   // (4,10,3)   fp32
    float* out = (float*)d_out;               // (16,256,10) fp32
    const int n_samples = in_sizes[0] / (2 * NQ);  // 4096
    qsim_kernel<<<n_samples / 2, 64, 0, stream>>>(x, w, out);
}